// Round 8
// baseline (703.012 us; speedup 1.0000x reference)
//
#include <hip/hip_runtime.h>

typedef unsigned short u16;
typedef unsigned int u32;
typedef __bf16 bf16x8 __attribute__((ext_vector_type(8)));
typedef float f32x4 __attribute__((ext_vector_type(4)));
typedef u32 u32x4 __attribute__((ext_vector_type(4)));
typedef u16 u16x4 __attribute__((ext_vector_type(4)));

#define NH 2048
#define BATCH 256
#define NIN 1024
#define NOUT 256
#define LAY 4
#define TSS 32
#define BK 64

#define WAITVM(N) asm volatile("s_waitcnt vmcnt(" #N ")" ::: "memory")

__device__ __forceinline__ u16 f2bf(float f) {
  u32 u = __builtin_bit_cast(u32, f);
  u = (u + 0x7FFFu + ((u >> 16) & 1u)) >> 16;
  return (u16)u;
}
__device__ __forceinline__ float bf2f(u16 h) {
  u32 u = ((u32)h) << 16;
  return __builtin_bit_cast(float, u);
}

// sin for |x| <= ~6, abs err < ~4e-6 (degree-9 odd, pi range reduction)
__device__ __forceinline__ float fast_sin(float x) {
  float k = __builtin_rintf(x * 0.3183098861837907f);
  float r = __builtin_fmaf(k, -3.14159274101257324f, x);
  r = __builtin_fmaf(k, 8.742277657347586e-08f, r);
  float s = r * r;
  float p = __builtin_fmaf(s, 2.75573192e-06f, -1.98412698e-04f);
  p = __builtin_fmaf(s, p, 8.33333333e-03f);
  p = __builtin_fmaf(s, p, -1.66666667e-01f);
  p = r + r * s * p;
  int ki = (int)k;
  return (ki & 1) ? -p : p;
}

__device__ __forceinline__ bf16x8 ld_frag(const u16* p) {
  u32x4 r = *(const u32x4*)p;
  return __builtin_bit_cast(bf16x8, r);
}

__device__ __forceinline__ f32x4 mfma16(bf16x8 a, bf16x8 b, f32x4 c) {
  return __builtin_amdgcn_mfma_f32_16x16x32_bf16(a, b, c, 0, 0, 0);
}

__device__ __forceinline__ void gload16(const u16* g, u16* lds) {
  __builtin_amdgcn_global_load_lds(
      (__attribute__((address_space(1))) u32*)g,
      (__attribute__((address_space(3))) u32*)lds, 16, 0, 0);
}

// ---------------- pack / convert kernels ----------------

__global__ __launch_bounds__(256) void k_cvt(const float* __restrict__ in,
                                             u16* __restrict__ out, int n4) {
  int i = blockIdx.x * 256 + threadIdx.x;
  if (i >= n4) return;
  f32x4 v = ((const f32x4*)in)[i];
  u16x4 o;
  #pragma unroll
  for (int j = 0; j < 4; j++) o[j] = f2bf(v[j]);
  ((u16x4*)out)[i] = o;
}

__global__ __launch_bounds__(256) void k_split2(const float* __restrict__ in,
                                                u16* __restrict__ hi,
                                                u16* __restrict__ lo, int n4) {
  int i = blockIdx.x * 256 + threadIdx.x;
  if (i >= n4) return;
  f32x4 v = ((const f32x4*)in)[i];
  u16x4 hv, lv;
  #pragma unroll
  for (int j = 0; j < 4; j++) {
    u16 h = f2bf(v[j]);
    hv[j] = h;
    lv[j] = f2bf(v[j] - bf2f(h));
  }
  ((u16x4*)hi)[i] = hv;
  ((u16x4*)lo)[i] = lv;
}

// ---------------- x_in GEMM (r5-proven 2-phase structure, unchanged) --------

struct GemmArgs {
  const u16* A[4];
  const u16* B[4];
  void* G;
  int ldA, ldB, kiters, nl;
};

template <int OBF, int NKS>
__global__ __launch_bounds__(256, 2) void k_gemm(GemmArgs args) {
  __shared__ alignas(16) u16 Ab[2][128 * BK];
  __shared__ alignas(16) u16 Bb[2][128 * BK];

  int bid = blockIdx.x;
  int nl = args.nl;
  int l = bid % nl;
  int t1 = bid / nl;
  int ks = t1 & (NKS - 1);
  int t2 = t1 / NKS;
  int nt = t2 & 15;
  int mt = t2 >> 4;

  int tid = threadIdx.x;
  int w = tid >> 6, lane = tid & 63;
  int l15 = lane & 15, l4 = lane >> 4;
  int ldA = args.ldA, ldB = args.ldB;
  int kiters = args.kiters;

  const u16* Ag = args.A[l] + (size_t)(mt * 128) * ldA + ks * (kiters * BK);
  const u16* Bg = args.B[l] + (size_t)(nt * 128) * ldB + ks * (kiters * BK);

  int srow = w * 32 + (lane >> 3);
  int csrc = ((lane & 7) ^ (lane >> 3)) * 8;
  int agoff[4], bgoff[4], lbase[4];
  #pragma unroll
  for (int j = 0; j < 4; j++) {
    agoff[j] = (srow + j * 8) * ldA + csrc;
    bgoff[j] = (srow + j * 8) * ldB + csrc;
    lbase[j] = w * 2048 + j * 512;
  }

  int wr = w >> 1, wc = w & 1;

  f32x4 zero = {0.f, 0.f, 0.f, 0.f};
  f32x4 acc[4][4];
  #pragma unroll
  for (int m = 0; m < 4; m++)
    #pragma unroll
    for (int n = 0; n < 4; n++) acc[m][n] = zero;

  auto stage = [&](int bufi, int kb) {
    int k0 = kb * BK;
    #pragma unroll
    for (int j = 0; j < 4; j++) {
      gload16(Ag + agoff[j] + k0, &Ab[bufi][lbase[j]]);
      gload16(Bg + bgoff[j] + k0, &Bb[bufi][lbase[j]]);
    }
  };
  auto compute = [&](int bufi) {
    #pragma unroll
    for (int kk = 0; kk < 2; kk++) {
      int swz = ((kk * 4 + l4) ^ (l15 & 7)) * 8;
      bf16x8 a[4], b[4];
      #pragma unroll
      for (int m = 0; m < 4; m++)
        a[m] = ld_frag(&Ab[bufi][(wr * 64 + m * 16 + l15) * BK + swz]);
      #pragma unroll
      for (int n = 0; n < 4; n++)
        b[n] = ld_frag(&Bb[bufi][(wc * 64 + n * 16 + l15) * BK + swz]);
      #pragma unroll
      for (int m = 0; m < 4; m++)
        #pragma unroll
        for (int n = 0; n < 4; n++)
          acc[m][n] = mfma16(a[m], b[n], acc[m][n]);
    }
  };

  stage(0, 0);
  stage(1, 1);

  int cur = 0;
  for (int kb = 0; kb < kiters - 2; kb++) {
    WAITVM(8);
    __builtin_amdgcn_s_barrier();
    compute(cur);
    __builtin_amdgcn_s_barrier();
    stage(cur, kb + 2);
    cur ^= 1;
  }
  WAITVM(8);
  __builtin_amdgcn_s_barrier();
  compute(cur);
  cur ^= 1;
  WAITVM(0);
  __builtin_amdgcn_s_barrier();
  compute(cur);

  size_t obase = ((size_t)(ks * nl + l) * BATCH + mt * 128) * NH + nt * 128;
  if (OBF) {
    u16* Go = (u16*)args.G + obase;
    #pragma unroll
    for (int m = 0; m < 4; m++) {
      int row = wr * 64 + m * 16 + l4 * 4;
      #pragma unroll
      for (int n = 0; n < 4; n++) {
        int col = wc * 64 + n * 16 + l15;
        #pragma unroll
        for (int r = 0; r < 4; r++)
          Go[(size_t)(row + r) * NH + col] = f2bf(acc[m][n][r]);
      }
    }
  } else {
    float* Go = (float*)args.G + obase;
    #pragma unroll
    for (int m = 0; m < 4; m++) {
      int row = wr * 64 + m * 16 + l4 * 4;
      #pragma unroll
      for (int n = 0; n < 4; n++) {
        int col = wc * 64 + n * 16 + l15;
        #pragma unroll
        for (int r = 0; r < 4; r++)
          Go[(size_t)(row + r) * NH + col] = acc[m][n][r];
      }
    }
  }
}

// ---------------- recurrent GEMM: 256x128 tile, 8 waves, counted-vmcnt ------
// T3+T4 port of the m201 phase structure to our shape.
// Tile BM=256 (full M) x BN=128, BK=64, split-K=4 -> grid 256, 8 K-steps/block.
// 3 LDS buffers (A 32KB + B 16KB each = 144 KB total) -> staging never targets
// a buffer being read. 6 gload16/thread per K-step (A:4, B:2).
// Per K-step: vmcnt(6) -> barrier -> 2 phases of
//   {8 ds_read || 3 gload_lds(step k+2) -> barrier -> sched_barrier(0)
//    -> setprio(1) -> 16 MFMA -> setprio(0)}.
// vmcnt counted once per K-step, never 0 until tail (6 loads/step, 2 ahead).
// Swizzle: 16B-chunk ^= (row&7), inverse-swizzled global source (rule #21).
// Decode: l=bid&3, ks=(bid>>2)&3, nt=bid>>4. bid%16 = (l,ks) pair; each XCD
// owns 2 (l,ks) W K-slices (2 MB each) = 4 MB = its L2.

struct Gemm8Args {
  const u16* h;   // [LAY][BATCH][NH]
  const u16* Wb;  // [LAY][NH][NH]
  u16* Gp;        // 16 slabs [ks*LAY+l][BATCH][NH]
};

__global__ __launch_bounds__(512, 1) void k_gemm8(Gemm8Args args) {
  __shared__ alignas(16) u16 Ab[3][256 * BK];  // 96 KB
  __shared__ alignas(16) u16 Bb[3][128 * BK];  // 48 KB

  int bid = blockIdx.x;
  int l = bid & 3;
  int ks = (bid >> 2) & 3;
  int nt = bid >> 4;

  int tid = threadIdx.x;
  int w = tid >> 6, lane = tid & 63;
  int l15 = lane & 15, l4 = lane >> 4;
  int wr = w >> 1, wc = w & 1;  // 4M x 2N waves, 64x64 each

  const u16* Ag = args.h + (size_t)l * (BATCH * NH) + ks * 512;
  const u16* Bg = args.Wb + (size_t)l * (NH * NH) + (size_t)(nt * 128) * NH + ks * 512;

  // staging: load j covers rows [j*64, j*64+64); row = j*64 + (tid>>3),
  // chunkpos = tid&7, src chunk = chunkpos ^ (row&7) (rule #21 inverse swz).
  int srow = tid >> 3;
  int csrc = ((tid & 7) ^ (srow & 7)) * 8;
  int aoff[4], boff[2], albase[4], blbase[2];
  #pragma unroll
  for (int j = 0; j < 4; j++) {
    aoff[j] = (j * 64 + srow) * NH + csrc;
    albase[j] = j * 4096 + tid * 8;
  }
  #pragma unroll
  for (int j = 0; j < 2; j++) {
    boff[j] = (j * 64 + srow) * NH + csrc;
    blbase[j] = j * 4096 + tid * 8;
  }

  f32x4 zero = {0.f, 0.f, 0.f, 0.f};
  f32x4 acc[4][4];
  #pragma unroll
  for (int m = 0; m < 4; m++)
    #pragma unroll
    for (int n = 0; n < 4; n++) acc[m][n] = zero;

  // full-step stage (prologue only): 6 loads
  auto stage_all = [&](int bufi, int kb) {
    int k0 = kb * BK;
    #pragma unroll
    for (int j = 0; j < 4; j++) gload16(Ag + aoff[j] + k0, &Ab[bufi][albase[j]]);
    #pragma unroll
    for (int j = 0; j < 2; j++) gload16(Bg + boff[j] + k0, &Bb[bufi][blbase[j]]);
  };

  // prologue: steps 0,1 in flight (12 loads)
  stage_all(0, 0);
  stage_all(1, 1);

  int cur = 0;
  #pragma unroll 1
  for (int kb = 0; kb < 8; kb++) {
    if (kb < 7) {
      WAITVM(6);  // this wave's step-kb loads landed (next step's 6 in flight)
    } else {
      WAITVM(0);
    }
    __builtin_amdgcn_s_barrier();        // all waves' step-kb loads landed
    __builtin_amdgcn_sched_barrier(0);

    int nbuf = cur + 2;
    if (nbuf >= 3) nbuf -= 3;
    int k2 = (kb + 2) * BK;
    bool do_stage = (kb < 6);

    // ---- phase 0: kk=0 ----
    {
      int swz = (l4 ^ (l15 & 7)) * 8;
      bf16x8 a[4], b[4];
      #pragma unroll
      for (int m = 0; m < 4; m++)
        a[m] = ld_frag(&Ab[cur][(wr * 64 + m * 16 + l15) * BK + swz]);
      #pragma unroll
      for (int n = 0; n < 4; n++)
        b[n] = ld_frag(&Bb[cur][(wc * 64 + n * 16 + l15) * BK + swz]);
      if (do_stage) {
        gload16(Ag + aoff[0] + k2, &Ab[nbuf][albase[0]]);
        gload16(Ag + aoff[1] + k2, &Ab[nbuf][albase[1]]);
        gload16(Bg + boff[0] + k2, &Bb[nbuf][blbase[0]]);
      }
      __builtin_amdgcn_s_barrier();
      __builtin_amdgcn_sched_barrier(0);
      __builtin_amdgcn_s_setprio(1);
      #pragma unroll
      for (int m = 0; m < 4; m++)
        #pragma unroll
        for (int n = 0; n < 4; n++)
          acc[m][n] = mfma16(a[m], b[n], acc[m][n]);
      __builtin_amdgcn_s_setprio(0);
      __builtin_amdgcn_sched_barrier(0);
    }
    // ---- phase 1: kk=1 ----
    {
      int swz = ((4 + l4) ^ (l15 & 7)) * 8;
      bf16x8 a[4], b[4];
      #pragma unroll
      for (int m = 0; m < 4; m++)
        a[m] = ld_frag(&Ab[cur][(wr * 64 + m * 16 + l15) * BK + swz]);
      #pragma unroll
      for (int n = 0; n < 4; n++)
        b[n] = ld_frag(&Bb[cur][(wc * 64 + n * 16 + l15) * BK + swz]);
      if (do_stage) {
        gload16(Ag + aoff[2] + k2, &Ab[nbuf][albase[2]]);
        gload16(Ag + aoff[3] + k2, &Ab[nbuf][albase[3]]);
        gload16(Bg + boff[1] + k2, &Bb[nbuf][blbase[1]]);
      }
      __builtin_amdgcn_s_barrier();
      __builtin_amdgcn_sched_barrier(0);
      __builtin_amdgcn_s_setprio(1);
      #pragma unroll
      for (int m = 0; m < 4; m++)
        #pragma unroll
        for (int n = 0; n < 4; n++)
          acc[m][n] = mfma16(a[m], b[n], acc[m][n]);
      __builtin_amdgcn_s_setprio(0);
      __builtin_amdgcn_sched_barrier(0);
    }

    cur = cur + 1;
    if (cur == 3) cur = 0;
  }

  u16* Go = args.Gp + (size_t)(ks * LAY + l) * (BATCH * NH) + nt * 128;
  #pragma unroll
  for (int m = 0; m < 4; m++) {
    int row = wr * 64 + m * 16 + l4 * 4;
    #pragma unroll
    for (int n = 0; n < 4; n++) {
      int col = wc * 64 + n * 16 + l15;
      #pragma unroll
      for (int r = 0; r < 4; r++)
        Go[(size_t)(row + r) * NH + col] = f2bf(acc[m][n][r]);
    }
  }
}

// ---------------- element-wise sin chain (4 bf16 partials, r4-proven) -------
__global__ __launch_bounds__(256) void k_chain(const u16* __restrict__ Gp,
                                               const float* __restrict__ x_in,
                                               const float* __restrict__ brec,
                                               u16* __restrict__ hout) {
  int i = blockIdx.x * 256 + threadIdx.x;  // 131072 threads, 4 elems each
  int e = i * 4;
  int col = e & (NH - 1);
  f32x4 pre = *(const f32x4*)(x_in + e);
  #pragma unroll
  for (int l = 0; l < LAY; l++) {
    u16x4 g0 = *(const u16x4*)(Gp + (size_t)(0 * LAY + l) * (BATCH * NH) + e);
    u16x4 g1 = *(const u16x4*)(Gp + (size_t)(1 * LAY + l) * (BATCH * NH) + e);
    u16x4 g2 = *(const u16x4*)(Gp + (size_t)(2 * LAY + l) * (BATCH * NH) + e);
    u16x4 g3 = *(const u16x4*)(Gp + (size_t)(3 * LAY + l) * (BATCH * NH) + e);
    f32x4 bb = *(const f32x4*)(brec + l * NH + col);
    u16x4 hv;
    #pragma unroll
    for (int j = 0; j < 4; j++) {
      float v = fast_sin(pre[j] + (bf2f(g0[j]) + bf2f(g1[j])) +
                         (bf2f(g2[j]) + bf2f(g3[j])) + bb[j]);
      pre[j] = v;
      hv[j] = f2bf(v);
    }
    *(u16x4*)(hout + (size_t)l * (BATCH * NH) + e) = hv;
  }
}

// x_in = sum of 6 partial slices + bias (fp32 partials)
__global__ __launch_bounds__(256) void k_xin_fin(const float* __restrict__ Gp2,
                                                 const float* __restrict__ bin,
                                                 float* __restrict__ x_in) {
  int i = blockIdx.x * 256 + threadIdx.x;
  int e = i * 4;
  int col = e & (NH - 1);
  f32x4 s = *(const f32x4*)(bin + col);
  #pragma unroll
  for (int t = 0; t < 6; t++)
    s += *(const f32x4*)(Gp2 + (size_t)t * (BATCH * NH) + e);
  *(f32x4*)(x_in + e) = s;
}

// ---------------- output projection: out = h3 @ (Wh+Wl)^T + b ----------------
__global__ __launch_bounds__(64) void k_gemm_out(const u16* __restrict__ h3,
                                                 const u16* __restrict__ Wh,
                                                 const u16* __restrict__ Wl,
                                                 const float* __restrict__ bout,
                                                 float* __restrict__ out) {
  int bid = blockIdx.x;  // 128 = 8 mt x 16 nt
  int mt = bid & 7, nt = bid >> 3;
  int lane = threadIdx.x;
  int l15 = lane & 15, l4 = lane >> 4;
  f32x4 zero = {0.f, 0.f, 0.f, 0.f};
  f32x4 acc0 = zero, acc1 = zero;
  const u16* a0p = h3 + (size_t)(mt * 32 + l15) * NH + l4 * 8;
  const u16* a1p = a0p + 16 * NH;
  const u16* bhp = Wh + (size_t)(nt * 16 + l15) * NH + l4 * 8;
  const u16* blp = Wl + (size_t)(nt * 16 + l15) * NH + l4 * 8;
  for (int kb = 0; kb < 64; kb++) {
    bf16x8 a0 = ld_frag(a0p + kb * 32);
    bf16x8 a1 = ld_frag(a1p + kb * 32);
    bf16x8 bh = ld_frag(bhp + kb * 32);
    bf16x8 bl = ld_frag(blp + kb * 32);
    acc0 = mfma16(a0, bh, acc0);
    acc0 = mfma16(a0, bl, acc0);
    acc1 = mfma16(a1, bh, acc1);
    acc1 = mfma16(a1, bl, acc1);
  }
  float bo = bout[nt * 16 + l15];
  #pragma unroll
  for (int r = 0; r < 4; r++) {
    out[(size_t)(mt * 32 + l4 * 4 + r) * NOUT + nt * 16 + l15] = acc0[r] + bo;
    out[(size_t)(mt * 32 + 16 + l4 * 4 + r) * NOUT + nt * 16 + l15] = acc1[r] + bo;
  }
}

// ---------------- host ----------------

extern "C" void kernel_launch(void* const* d_in, const int* in_sizes, int n_in,
                              void* d_out, int out_size, void* d_ws, size_t ws_size,
                              hipStream_t stream) {
  const float* X     = (const float*)d_in[0];
  const float* Winw  = (const float*)d_in[1];
  const float* Winb  = (const float*)d_in[2];
  const float* Wrw   = (const float*)d_in[3];
  const float* Wrb   = (const float*)d_in[4];
  const float* Woutw = (const float*)d_in[5];
  const float* Woutb = (const float*)d_in[6];
  float* out = (float*)d_out;

  char* ws = (char*)d_ws;
  u16* Wb     = (u16*)(ws);                    // 32 MB  bf16 W_rec
  u16* h0     = (u16*)(ws + 33554432);         // 4 MB
  u16* h1     = (u16*)(ws + 37748736);         // 4 MB
  float* xin  = (float*)(ws + 41943040);       // 2 MB
  u16* Gp     = (u16*)(ws + 44040192);         // 16 MB bf16 (4 ks x 4 l)
  float* Gp2  = (float*)(ws + 60817408);       // 12 MB fp32 (2 ks x 3 terms)
  u16* Xhi    = (u16*)(ws + 73400320);         // 512 KB
  u16* Xlo    = (u16*)(ws + 73924608);         // 512 KB
  u16* Winh   = (u16*)(ws + 74448896);         // 4 MB
  u16* Winl   = (u16*)(ws + 78643200);         // 4 MB
  u16* Wouth  = (u16*)(ws + 82837504);         // 1 MB
  u16* Woutl  = (u16*)(ws + 83886080);         // 1 MB -> end 84934656

  // pack weights (every call; stateless)
  k_cvt<<<16384, 256, 0, stream>>>(Wrw, Wb, 4194304);
  k_split2<<<256, 256, 0, stream>>>(X, Xhi, Xlo, 65536);
  k_split2<<<2048, 256, 0, stream>>>(Winw, Winh, Winl, 524288);
  k_split2<<<512, 256, 0, stream>>>(Woutw, Wouth, Woutl, 131072);
  hipMemsetAsync(h0, 0, 4194304, stream);

  // x_in = X @ W_in^T (+bias), 3-term bf16 split, fp32 partials, split-K 2
  GemmArgs ax;
  ax.A[0] = Xhi; ax.A[1] = Xhi; ax.A[2] = Xlo; ax.A[3] = Xhi;
  ax.B[0] = Winh; ax.B[1] = Winl; ax.B[2] = Winh; ax.B[3] = Winh;
  ax.G = Gp2; ax.ldA = NIN; ax.ldB = NIN; ax.kiters = 8; ax.nl = 3;
  k_gemm<0, 2><<<192, 256, 0, stream>>>(ax);
  k_xin_fin<<<512, 256, 0, stream>>>(Gp2, Winb, xin);

  u16* hin = h0;
  u16* hout = h1;
  for (int t = 0; t < TSS; t++) {
    Gemm8Args ar;
    ar.h = hin; ar.Wb = Wb; ar.Gp = Gp;
    k_gemm8<<<256, 512, 0, stream>>>(ar);
    k_chain<<<512, 256, 0, stream>>>(Gp, xin, Wrb, hout);
    u16* tmp = hin; hin = hout; hout = tmp;
  }

  // final layer-3 hidden state lives in h0 (32 swaps); output projection
  k_gemm_out<<<128, 64, 0, stream>>>(h0 + (size_t)3 * (BATCH * NH), Wouth, Woutl,
                                     Woutb, out);
}